// Round 8
// baseline (65013.190 us; speedup 1.0000x reference)
//
#include <hip/hip_runtime.h>
#include <stdint.h>

#define DEV static __device__ __forceinline__

namespace {
constexpr int Bx = 16, ENCx = 512, DECx = 800, Dx = 256, Hx = 1024;
constexpr int NBLK = 256, NTHR = 512;

// ---- workspace float offsets ----
constexpr int WS_HBUF = 0;                      // 2 * B*H (double-buffered h master)
constexpr int WS_CTX  = WS_HBUF + 2*Bx*Hx;      // B*D (nctx contiguous after)
constexpr int WS_NCTX = WS_CTX  + Bx*Dx;        // B*D
constexpr int WS_X1   = WS_NCTX + Bx*Dx;        // B*D
constexpr int WS_AL   = WS_X1   + Bx*Dx;        // B*ENC
constexpr int WS_FEND = WS_AL   + Bx*ENCx;
// ---- int offsets (relative to wsf + WS_FEND) ----
constexpr int IW_F1   = 0;                      // flag1[DEC]
constexpr int IW_F2   = IW_F1 + DECx;           // flag2[DEC*16]
constexpr int IW_SLOT = ((IW_F2 + DECx*16 + 63)/64)*64;  // 256 barrier slots
constexpr int IW_GEN  = IW_SLOT + 256 + 64;     // 8 replicated gen words, stride 32
constexpr int IW_END  = IW_GEN + 256;
constexpr size_t CTXOUT = (size_t)Bx*DECx*Dx;

// ---- dynamic LDS float offsets ----
constexpr int LH_STR = 1028;                    // padded h stride
constexpr int CT_STR = 260;                     // padded ctx stride
constexpr int LW_H   = 0;                       // 16*1028 (h; reused as 32*260 ctx|nctx)
constexpr int LW_WHH = LW_H + 16*LH_STR;        // 16384 Whh rows
constexpr int LW_TS  = LW_WHH + 16384;          // union (head weights / slice buffers)
constexpr int TS_WLT = 0, TS_BLN = 6144, TS_X1L = 6168, TS_X2P = 6424, TS_X2L = 6936;
constexpr int TS_CPN = 0, TS_ALB = 1024;
constexpr int LDS_DYN_F = LW_TS + 7192;
constexpr size_t SMEM_BYTES = (size_t)LDS_DYN_F * 4;   // 160096 B
}

DEV float frcp(float x){ return __builtin_amdgcn_rcpf(x); }
DEV float sigm(float x){ return frcp(1.0f + __expf(-x)); }
DEV float ftanh(float x){
  x = fminf(fmaxf(x, -15.0f), 15.0f);
  float e = __expf(2.0f*x);
  return (e - 1.0f) * frcp(e + 1.0f);
}
DEV float wred16(float v){
  v += __shfl_xor(v, 1); v += __shfl_xor(v, 2);
  v += __shfl_xor(v, 4); v += __shfl_xor(v, 8);
  return v;
}
DEV int   ld_rlx(const int* p){ return __hip_atomic_load(p, __ATOMIC_RELAXED, __HIP_MEMORY_SCOPE_AGENT); }
DEV void  st_rlx(int* p, int v){ __hip_atomic_store(p, v, __ATOMIC_RELAXED, __HIP_MEMORY_SCOPE_AGENT); }
DEV float ldf_c(const float* p){ return __hip_atomic_load(p, __ATOMIC_RELAXED, __HIP_MEMORY_SCOPE_AGENT); }
DEV void  stf_c(float* p, float v){ __hip_atomic_store(p, v, __ATOMIC_RELAXED, __HIP_MEMORY_SCOPE_AGENT); }
DEV void cbar(){ asm volatile("" ::: "memory"); }

// dependent-FMA filler: keeps the SIMD issuing (anti-DVFS), throttles poll rate
DEV void spin_fma(){
  float x = 1.0f;
  #pragma unroll
  for (int i = 0; i < 16; ++i) x = fmaf(x, 1.0000001f, 1e-9f);
  asm volatile("" :: "v"(x));
}

// sc1 bulk loads: issue + wait INSIDE one asm block (no cross-region live asm outputs)
DEV void ld8_wait(float4 (&r)[8], const float* p){
  const float *a1=p+2048,*a2=p+4096,*a3=p+6144,*a4=p+8192,*a5=p+10240,*a6=p+12288,*a7=p+14336;
  asm volatile(
    "global_load_dwordx4 %0, %8, off sc1\n\t"
    "global_load_dwordx4 %1, %9, off sc1\n\t"
    "global_load_dwordx4 %2, %10, off sc1\n\t"
    "global_load_dwordx4 %3, %11, off sc1\n\t"
    "global_load_dwordx4 %4, %12, off sc1\n\t"
    "global_load_dwordx4 %5, %13, off sc1\n\t"
    "global_load_dwordx4 %6, %14, off sc1\n\t"
    "global_load_dwordx4 %7, %15, off sc1\n\t"
    "s_waitcnt vmcnt(0)"
    : "=&v"(r[0]),"=&v"(r[1]),"=&v"(r[2]),"=&v"(r[3]),
      "=&v"(r[4]),"=&v"(r[5]),"=&v"(r[6]),"=&v"(r[7])
    : "v"(p),"v"(a1),"v"(a2),"v"(a3),"v"(a4),"v"(a5),"v"(a6),"v"(a7)
    : "memory");
}
DEV void ld4_wait(float4 (&r)[4], const float* p){
  const float *a1=p+2048,*a2=p+4096,*a3=p+6144;
  asm volatile(
    "global_load_dwordx4 %0, %4, off sc1\n\t"
    "global_load_dwordx4 %1, %5, off sc1\n\t"
    "global_load_dwordx4 %2, %6, off sc1\n\t"
    "global_load_dwordx4 %3, %7, off sc1\n\t"
    "s_waitcnt vmcnt(0)"
    : "=&v"(r[0]),"=&v"(r[1]),"=&v"(r[2]),"=&v"(r[3])
    : "v"(p),"v"(a1),"v"(a2),"v"(a3)
    : "memory");
}
DEV int4 ld4i_sc1(const int* p){
  int4 r;
  asm volatile("global_load_dwordx4 %0, %1, off sc1\n\ts_waitcnt vmcnt(0)"
    : "=&v"(r) : "v"(p) : "memory");      // early-clobber: address must survive for the loop
  return r;
}

// all-wave wait: wave0 polls global, stamps LDS; waves 1..7 spin on LDS with FMA filler
DEV void wait_flag(int* p, int target, volatile int* lslot, int stamp){
  const int tid = threadIdx.x;
  if (tid < 64){
    while (ld_rlx(p) < target) spin_fma();
    if (tid == 0) *lslot = stamp;
  } else {
    while (*lslot < stamp) spin_fma();
  }
  __syncthreads();
  cbar();
}

// slot barrier: block0 gathers 4 slots/lane with ONE dwordx4 per poll iteration
DEV void gridbar(int* slots, int* genp, unsigned &gen, volatile int* lgen){
  const int next = (int)(gen + 1u);
  const int tid = threadIdx.x;
  __syncthreads();                       // drains vmcnt: sc1 stores at coherence point
  if (tid == 0) st_rlx(slots + blockIdx.x, next);
  if (blockIdx.x == 0){
    if (tid < 64){
      const int* my = slots + tid*4;
      for (;;){
        int4 v = ld4i_sc1(my);
        bool ok = (v.x >= next) & (v.y >= next) & (v.z >= next) & (v.w >= next);
        if (__ballot(ok) == ~0ull) break;
        spin_fma();
      }
      if (tid < 8) st_rlx(genp + tid*32, next);
      if (tid == 0) *lgen = next;
    } else {
      while (*lgen < next) spin_fma();
    }
  } else {
    if (tid < 64){
      int* g = genp + (blockIdx.x & 7)*32;
      while (ld_rlx(g) < next) spin_fma();
      if (tid == 0) *lgen = next;
    } else {
      while (*lgen < next) spin_fma();
    }
  }
  __syncthreads();
  cbar();
  gen = (unsigned)next;
}

DEV void gchunk(float (&acc)[2][4], float4 wa, float4 wb, const float* xlane, size_t xstride, int b4){
  #pragma unroll
  for (int bi = 0; bi < 4; ++bi){
    float4 xv = *reinterpret_cast<const float4*>(xlane + (size_t)(b4*4 + bi)*xstride);
    acc[0][bi] = fmaf(wa.x,xv.x, fmaf(wa.y,xv.y, fmaf(wa.z,xv.z, fmaf(wa.w,xv.w, acc[0][bi]))));
    acc[1][bi] = fmaf(wb.x,xv.x, fmaf(wb.y,xv.y, fmaf(wb.z,xv.z, fmaf(wb.w,xv.w, acc[1][bi]))));
  }
}

extern "C" __global__ void gmm_init(float* wsf){
  int* wsi = (int*)(wsf + WS_FEND);
  int idx = blockIdx.x*blockDim.x + threadIdx.x;
  for (int k = idx; k < IW_END; k += gridDim.x*blockDim.x) wsi[k] = 0;
}

extern "C" __global__ void __launch_bounds__(NTHR, 1) gmm_main(
    const float* __restrict__ enc, const float* __restrict__ mel,
    const int* __restrict__ outlen, const int* __restrict__ condlen,
    const float* __restrict__ Wih, const float* __restrict__ Whh,
    const float* __restrict__ bih, const float* __restrict__ bhh,
    const float* __restrict__ W1,  const float* __restrict__ b1v,
    const float* __restrict__ W2,  const float* __restrict__ Wlin,
    const float* __restrict__ blin,
    float* __restrict__ out, float* __restrict__ wsf)
{
  const int bk = blockIdx.x, tid = threadIdx.x;
  const int lane = tid & 63;
  const int klane4 = (tid & 15) * 4;
  const int b4 = (tid >> 4) & 3;
  const int wid = tid >> 6;

  int* wsi   = (int*)(wsf + WS_FEND);
  int* flag1 = wsi + IW_F1;
  int* flag2 = wsi + IW_F2;
  int* slots = wsi + IW_SLOT;
  int* genp  = wsi + IW_GEN;
  float* hb0    = wsf + WS_HBUF;
  float* ctxws  = wsf + WS_CTX;     // nctx contiguous at +4096
  float* x1ws   = wsf + WS_X1;
  float* alws   = wsf + WS_AL;

  extern __shared__ float lds[];
  float* lh   = lds + LW_H;
  float* lwhh = lds + LW_WHH;
  float* lts  = lds + LW_TS;

  __shared__ float g_lds[256];
  __shared__ float bsum[16];
  __shared__ float cl[64];
  __shared__ float outl[32];
  __shared__ float mixw[8], mixlc[8], mixis[8];
  __shared__ float locl[8];
  __shared__ int   s_cond, s_olen;
  __shared__ int   lf1, lf2, lgenv;

  if (tid == 0){ lf1 = 0; lf2 = 0; lgenv = 0; }

  const int jidx0 = 2*wid;
  const int j0 = (jidx0 >> 2)*1024 + bk*4 + (jidx0 & 3);
  const int j1 = ((jidx0+1) >> 2)*1024 + bk*4 + ((jidx0+1) & 3);
  const float* WihR0 = Wih + (size_t)j0*768;   // read-only -> L2-resident
  const float* WihR1 = Wih + (size_t)j1*768;

  const bool is_x1   = (bk < 32);
  const bool is_head = (bk >= 32 && bk < 48);
  const int  hbb     = bk - 32;

  int sl_cb = 0, sl_dc0 = 0, sl_n = 0;
  if (!is_head){
    int idx = (bk < 32) ? bk : (bk - 16);
    if (idx < 16){ sl_cb = idx; sl_dc0 = 14; sl_n = 2; }
    else { int j = idx - 16; sl_cb = j / 14; sl_dc0 = j % 14; sl_n = 1; }
  }

  // ---------------- one-time staging ----------------
  #pragma unroll
  for (int jj = jidx0; jj <= jidx0 + 1; ++jj){
    const int gj = (jj >> 2)*1024 + bk*4 + (jj & 3);
    float4* dst = (float4*)(lwhh + jj*1024);
    const float4* s = (const float4*)(Whh + (size_t)gj*1024);
    for (int i = lane; i < 256; i += 64) dst[i] = s[i];
  }
  if (tid < 16){
    int g = tid >> 2, ul = tid & 3, u = bk*4 + ul;
    bsum[tid] = bih[g*1024 + u] + bhh[g*1024 + u];
  }
  float4 w2r[32];
  if (is_head){
    for (int i = tid; i < 6144; i += NTHR){
      int k = i / 24, r = i % 24;
      lts[TS_WLT + i] = Wlin[(size_t)r*256 + k];
    }
    if (tid < 24) lts[TS_BLN + tid] = blin[tid];
    if (tid == 0){ s_cond = condlen[hbb]; s_olen = outlen[hbb]; }
    if (tid < 8) locl[tid] = -0.1f;
    {
      int r = tid >> 1, hf = tid & 1;
      const float* w2row = W2 + (size_t)r*256 + hf*128;
      #pragma unroll
      for (int i = 0; i < 32; ++i) w2r[i] = *reinterpret_cast<const float4*>(w2row + i*4);
    }
  }
  __syncthreads();

  auto write_h = [&](int t){
    float4 r[8];
    ld8_wait(r, hb0 + (t & 1)*(Bx*Hx) + tid*4);
    #pragma unroll
    for (int i = 0; i < 8; ++i){
      int rr = 2*i + (tid >> 8);
      *reinterpret_cast<float4*>(lh + rr*LH_STR + (tid & 255)*4) = r[i];
    }
    __syncthreads();
  };

  auto ctx_slice = [&](int cb, int dc, int t){
    int d0 = dc * 16;
    int dl = tid & 15, eg = tid >> 4;
    int d = d0 + dl;
    const float* encb = enc + (size_t)cb*ENCx*Dx;
    const float* albl = lts + TS_ALB;
    float* cpn = lts + TS_CPN;
    float ca = 0.f, na = 0.f;
    #pragma unroll
    for (int i = 0; i < 16; ++i){
      int e = eg*16 + i;
      float av = albl[e];
      float nv = albl[(e + 511) & 511];
      float ev = encb[(size_t)e*256 + d];
      ca = fmaf(av, ev, ca);
      na = fmaf(nv, ev, na);
    }
    cpn[0*512 + eg*16 + dl] = ca;
    cpn[1*512 + eg*16 + dl] = na;
    __syncthreads();
    if (tid < 32){
      int z = tid >> 4, dd = tid & 15;
      float sum = 0.f;
      #pragma unroll
      for (int g2 = 0; g2 < 32; ++g2) sum += cpn[z*512 + g2*16 + dd];
      if (z == 0){
        stf_c(ctxws + cb*256 + d0 + dd, sum);
        out[(size_t)cb*((size_t)DECx*Dx) + (size_t)t*Dx + d0 + dd] = sum;
      } else {
        stf_c(ctxws + 4096 + cb*256 + d0 + dd, sum);   // nctx master
      }
    }
    __syncthreads();
  };

  unsigned gen = 0;

  // ---------------- prologue: gates t=0 (q=[mel0, 0, enc[:,0,:]], h=0, c=0) ----------------
  {
    float acc[2][4] = {{0,0,0,0},{0,0,0,0}};
    #pragma unroll
    for (int it = 0; it < 4; ++it){
      int k = it*64 + klane4;
      gchunk(acc, *(const float4*)(WihR0 + k), *(const float4*)(WihR1 + k),
             mel + k, (size_t)DECx*Dx, b4);
    }
    #pragma unroll
    for (int it = 0; it < 4; ++it){
      int k = it*64 + klane4;
      gchunk(acc, *(const float4*)(WihR0 + 512 + k), *(const float4*)(WihR1 + 512 + k),
             enc + k, (size_t)ENCx*Dx, b4);
    }
    #pragma unroll
    for (int jj = 0; jj < 2; ++jj)
      #pragma unroll
      for (int bi = 0; bi < 4; ++bi){
        float v = wred16(acc[jj][bi]);
        if ((tid & 15) == 0) g_lds[(jidx0 + jj)*16 + b4*4 + bi] = v;
      }
    __syncthreads();
    if (tid < 64){
      int b = tid & 15, ul = tid >> 4, u = bk*4 + ul;
      float gi = g_lds[( 0 + ul)*16 + b] + bsum[ul];
      float gg = g_lds[( 8 + ul)*16 + b] + bsum[8 + ul];
      float go = g_lds[(12 + ul)*16 + b] + bsum[12 + ul];
      float c2 = sigm(gi) * ftanh(gg);
      float h2 = sigm(go) * ftanh(c2);
      cl[b*4 + ul] = c2;
      stf_c(hb0 + b*1024 + u, h2);
    }
  }
  gridbar(slots, genp, gen, &lgenv);

  // ---------------- main loop ----------------
  for (int t = 0; t < DECx; ++t){
    float acc[2][4] = {{0,0,0,0},{0,0,0,0}};

    if (is_x1){
      // x1 is on the critical path: stage h immediately
      write_h(t);
      int d = bk*8 + wid;
      const float* W1r = W1 + (size_t)d*1024;
      float a4[4] = {0,0,0,0};
      #pragma unroll 4
      for (int it = 0; it < 16; ++it){
        int k = it*64 + klane4;
        float4 wq = *(const float4*)(W1r + k);
        #pragma unroll
        for (int bi = 0; bi < 4; ++bi){
          float4 xv = *(const float4*)(lh + (size_t)(b4*4 + bi)*LH_STR + k);
          a4[bi] = fmaf(wq.x,xv.x, fmaf(wq.y,xv.y, fmaf(wq.z,xv.z, fmaf(wq.w,xv.w, a4[bi]))));
        }
      }
      #pragma unroll
      for (int bi = 0; bi < 4; ++bi){
        float v = wred16(a4[bi]);
        if ((tid & 15) == 0){
          v += b1v[d];
          v = (v >= 0.f) ? v : 0.1f*v;
          stf_c(x1ws + (b4*4 + bi)*256 + d, v);
        }
      }
      __syncthreads();                     // vmcnt(0): x1 at coherence point
      if (tid == 0)
        __hip_atomic_fetch_add(flag1 + t, 1, __ATOMIC_RELAXED, __HIP_MEMORY_SCOPE_AGENT);
      // region 1a+1b while head runs
      if (t < DECx - 1){
        const int tt = t + 1;
        #pragma unroll
        for (int it = 0; it < 4; ++it){
          int k = it*64 + klane4;
          gchunk(acc, *(const float4*)(WihR0 + k), *(const float4*)(WihR1 + k),
                 mel + (size_t)tt*Dx + k, (size_t)DECx*Dx, b4);
        }
        #pragma unroll 4
        for (int it = 0; it < 16; ++it){
          int k = it*64 + klane4;
          gchunk(acc, *(const float4*)(lwhh + jidx0*1024 + k), *(const float4*)(lwhh + (jidx0+1)*1024 + k),
                 lh + k, LH_STR, b4);
        }
      }
    } else if (is_head){
      // mel partial first (hides flag1 latency)
      if (t < DECx - 1){
        const int tt = t + 1;
        #pragma unroll
        for (int it = 0; it < 4; ++it){
          int k = it*64 + klane4;
          gchunk(acc, *(const float4*)(WihR0 + k), *(const float4*)(WihR1 + k),
                 mel + (size_t)tt*Dx + k, (size_t)DECx*Dx, b4);
        }
      }
      wait_flag(flag1 + t, 32, &lf1, t + 1);
      if (tid < 256) lts[TS_X1L + tid] = ldf_c(x1ws + hbb*256 + tid);
      __syncthreads();
      {
        int hf = tid & 1;
        const float* x1b = lts + TS_X1L + hf*128;
        float a = 0.f;
        #pragma unroll
        for (int i = 0; i < 32; ++i){
          float4 xv = *(const float4*)(x1b + i*4);
          a = fmaf(w2r[i].x,xv.x, fmaf(w2r[i].y,xv.y, fmaf(w2r[i].z,xv.z, fmaf(w2r[i].w,xv.w, a))));
        }
        lts[TS_X2P + tid] = a;
      }
      __syncthreads();
      if (tid < 256) lts[TS_X2L + tid] = ftanh(lts[TS_X2P + 2*tid] + lts[TS_X2P + 2*tid + 1]);
      __syncthreads();
      if (tid < 24){
        float s = lts[TS_BLN + tid];
        #pragma unroll 8
        for (int k = 0; k < 256; ++k) s = fmaf(lts[TS_X2L + k], lts[TS_WLT + k*24 + tid], s);
        outl[tid] = s;
      }
      __syncthreads();
      if (tid < 8){
        float w = outl[tid];
        float mx = w;
        mx = fmaxf(mx, __shfl_xor(mx, 1)); mx = fmaxf(mx, __shfl_xor(mx, 2)); mx = fmaxf(mx, __shfl_xor(mx, 4));
        float e = __expf(w - mx);
        float sum = e;
        sum += __shfl_xor(sum, 1); sum += __shfl_xor(sum, 2); sum += __shfl_xor(sum, 4);
        mixw[tid] = e * frcp(sum);
        float cm1 = (float)s_cond - 1.0f;
        float dl = sigm(outl[8 + tid]) + 0.005f;
        float lc = locl[tid] + dl;
        mixlc[tid] = lc;
        locl[tid]  = fminf(lc, cm1);
        mixis[tid] = 1.0f + __expf(-outl[16 + tid]);
      }
      __syncthreads();
      {
        float e = (float)tid;
        float a = 0.f;
        #pragma unroll
        for (int m = 0; m < 8; ++m){
          float df = mixlc[m] - e;
          a += (ftanh((df + 0.5f)*mixis[m]) - ftanh((df - 0.5f)*mixis[m])) * mixw[m];
        }
        a *= 0.5f;
        bool valid = (tid < s_cond) && (t < s_olen);
        if (!valid) a = 0.f;
        stf_c(alws + hbb*512 + tid, a);
        out[CTXOUT + (size_t)hbb*((size_t)DECx*ENCx) + (size_t)t*ENCx + tid] = a;
      }
      __syncthreads();                     // vmcnt(0): align at coherence point
      if (tid == 0) st_rlx(flag2 + t*16 + hbb, 1);
      // now stage h and do region 1b
      write_h(t);
      if (t < DECx - 1){
        #pragma unroll 4
        for (int it = 0; it < 16; ++it){
          int k = it*64 + klane4;
          gchunk(acc, *(const float4*)(lwhh + jidx0*1024 + k), *(const float4*)(lwhh + (jidx0+1)*1024 + k),
                 lh + k, LH_STR, b4);
        }
      }
    } else {
      // slice blocks: mel partial, then stage h, then Whh partial
      if (t < DECx - 1){
        const int tt = t + 1;
        #pragma unroll
        for (int it = 0; it < 4; ++it){
          int k = it*64 + klane4;
          gchunk(acc, *(const float4*)(WihR0 + k), *(const float4*)(WihR1 + k),
                 mel + (size_t)tt*Dx + k, (size_t)DECx*Dx, b4);
        }
      }
      write_h(t);
      if (t < DECx - 1){
        #pragma unroll 4
        for (int it = 0; it < 16; ++it){
          int k = it*64 + klane4;
          gchunk(acc, *(const float4*)(lwhh + jidx0*1024 + k), *(const float4*)(lwhh + (jidx0+1)*1024 + k),
                 lh + k, LH_STR, b4);
        }
      }
    }

    // ---- ctx duty (head exempt)
    if (!is_head){
      wait_flag(flag2 + t*16 + sl_cb, 1, &lf2, t + 1);
      lts[TS_ALB + tid] = ldf_c(alws + sl_cb*512 + tid);
      __syncthreads();
      ctx_slice(sl_cb, sl_dc0, t);
      if (sl_n == 2) ctx_slice(sl_cb, sl_dc0 + 1, t);
    }

    gridbar(slots, genp, gen, &lgenv);   // barrier A: ctx/nctx masters published

    // ---- region 2: stage ctx|nctx, gate part + cell -> h_{t+1}
    if (t < DECx - 1){
      {
        float4 cr[4];
        ld4_wait(cr, ctxws + tid*4);      // 8192 contiguous floats: ctx then nctx
        #pragma unroll
        for (int i = 0; i < 4; ++i){
          int r = 8*i + (tid >> 6);
          *reinterpret_cast<float4*>(lh + r*CT_STR + (tid & 63)*4) = cr[i];
        }
      }
      __syncthreads();
      #pragma unroll
      for (int it = 0; it < 4; ++it){
        int k = it*64 + klane4;
        gchunk(acc, *(const float4*)(WihR0 + 256 + k), *(const float4*)(WihR1 + 256 + k),
               lh + k, CT_STR, b4);
      }
      #pragma unroll
      for (int it = 0; it < 4; ++it){
        int k = it*64 + klane4;
        gchunk(acc, *(const float4*)(WihR0 + 512 + k), *(const float4*)(WihR1 + 512 + k),
               lh + 16*CT_STR + k, CT_STR, b4);
      }
      #pragma unroll
      for (int jj = 0; jj < 2; ++jj)
        #pragma unroll
        for (int bi = 0; bi < 4; ++bi){
          float v = wred16(acc[jj][bi]);
          if ((tid & 15) == 0) g_lds[(jidx0 + jj)*16 + b4*4 + bi] = v;
        }
      __syncthreads();
      if (tid < 64){
        int b = tid & 15, ul = tid >> 4, u = bk*4 + ul;
        float gi = g_lds[( 0 + ul)*16 + b] + bsum[ul];
        float gf = g_lds[( 4 + ul)*16 + b] + bsum[4 + ul];
        float gg = g_lds[( 8 + ul)*16 + b] + bsum[8 + ul];
        float go = g_lds[(12 + ul)*16 + b] + bsum[12 + ul];
        float co = cl[b*4 + ul];
        float c2 = sigm(gf)*co + sigm(gi)*ftanh(gg);
        float h2 = sigm(go)*ftanh(c2);
        cl[b*4 + ul] = c2;
        stf_c(hb0 + ((t + 1) & 1)*(Bx*Hx) + b*1024 + u, h2);
      }
    }

    gridbar(slots, genp, gen, &lgenv);   // barrier B: h_{t+1} master published
  }
}

extern "C" void kernel_launch(void* const* d_in, const int* in_sizes, int n_in,
                              void* d_out, int out_size, void* d_ws, size_t ws_size,
                              hipStream_t stream)
{
  const float* enc    = (const float*)d_in[0];
  const float* mel    = (const float*)d_in[1];
  const int*   outlen = (const int*)d_in[3];
  const int*   cond   = (const int*)d_in[4];
  const float* Wih    = (const float*)d_in[5];
  const float* Whh    = (const float*)d_in[6];
  const float* bih    = (const float*)d_in[7];
  const float* bhh    = (const float*)d_in[8];
  const float* W1     = (const float*)d_in[9];
  const float* b1v    = (const float*)d_in[10];
  const float* W2     = (const float*)d_in[11];
  const float* Wlin   = (const float*)d_in[12];
  const float* blin   = (const float*)d_in[13];
  float* outp = (float*)d_out;
  float* wsf  = (float*)d_ws;

  (void)hipFuncSetAttribute((const void*)gmm_main,
                            hipFuncAttributeMaxDynamicSharedMemorySize,
                            (int)SMEM_BYTES);

  hipLaunchKernelGGL(gmm_init, dim3(64), dim3(256), 0, stream, wsf);

  void* args[] = {
    (void*)&enc, (void*)&mel, (void*)&outlen, (void*)&cond,
    (void*)&Wih, (void*)&Whh, (void*)&bih, (void*)&bhh,
    (void*)&W1, (void*)&b1v, (void*)&W2, (void*)&Wlin, (void*)&blin,
    (void*)&outp, (void*)&wsf
  };
  (void)hipLaunchCooperativeKernel((void*)gmm_main, dim3(NBLK), dim3(NTHR),
                                   args, SMEM_BYTES, stream);
}